// Round 8
// baseline (279.401 us; speedup 1.0000x reference)
//
#include <hip/hip_runtime.h>
#include <math.h>

#define NPIX 9216        // 96*96
#define SCALE 0.17677669529663687f
#define LOG2E 1.4426950408889634f
#define PSL   (SCALE * LOG2E)            // baked into Q at proj epilogue
#define RINV  5.656854249492381f         // 1/SCALE, baked into relb

typedef __attribute__((ext_vector_type(8))) short bh8;   // 8 x bf16 (4 VGPRs)
typedef __attribute__((ext_vector_type(4))) float f4;    // MFMA C/D + indexable float4

__device__ __forceinline__ unsigned short f2bf(float f) {
    unsigned u = __float_as_uint(f);
    u += 0x7fff + ((u >> 16) & 1);          // RNE
    return (unsigned short)(u >> 16);
}
__device__ __forceinline__ void gload_lds16(const void* g, void* l) {
    __builtin_amdgcn_global_load_lds(
        (const __attribute__((address_space(1))) unsigned int*)g,
        (__attribute__((address_space(3))) unsigned int*)l, 16, 0, 0);
}

// ---------------------------------------------------------------------------
// Kernel 0: W (q;kv) fp32 -> bf16 [768][256]; blocks 768+: hrel/wrel fp32 ->
// bf16 relb[2][32][32], pre-scaled by 1/SCALE (Q carries SCALE*LOG2E),
// rows >=27 zeroed.
// ---------------------------------------------------------------------------
__global__ void wconv_kernel(const float* __restrict__ qw, const float* __restrict__ kvw,
                             const float* __restrict__ hrel, const float* __restrict__ wrel,
                             unsigned short* __restrict__ Wb,
                             unsigned short* __restrict__ relb) {
    int bid = blockIdx.x, tid = threadIdx.x;
    if (bid < 768) {
        float v = (bid < 256) ? qw[bid * 256 + tid] : kvw[(bid - 256) * 256 + tid];
        Wb[bid * 256 + tid] = f2bf(v);
    } else {
        int e = (bid - 768) * 256 + tid;      // [0, 2048)
        int half = e >> 10, r = (e >> 5) & 31, d = e & 31;
        float v = 0.0f;
        if (r < 27) v = (half ? wrel : hrel)[r * 32 + d] * RINV;
        relb[half * 1024 + r * 32 + d] = f2bf(v);
    }
}

// ---------------------------------------------------------------------------
// Kernel 1 (was kernel 2): projection GEMM with FUSED transpose staging.
// xtrans is deleted: proj reads x[b][256 ch][9216 pix] fp32 directly.
// A-staging per k-step: thread (tid) = 16 pix-lanes x 16 ch-pair groups;
//   loads 2x2 float4 row-segments (coalesced 16-lane x 16B), cvt_pk packs
//   (ch,ch+1) -> b32 write into As[pix][ch] with byte ^= ((pix>>3)&3)<<5
//   (4-way write conflicts; af b128 reads apply the same XOR, 16-bank
//   pattern identical to the previous linear layout).
// B-staging: gload_lds16 (unchanged). MFMA + LDS epilogue unchanged;
// Q pre-scaled by PSL.
// ---------------------------------------------------------------------------
__global__ __launch_bounds__(256) void proj_kernel(const float* __restrict__ x,
                                                   const unsigned short* __restrict__ Wb,
                                                   unsigned short* __restrict__ qb,
                                                   unsigned short* __restrict__ kvb) {
    int flat = blockIdx.x + 72 * (blockIdx.y + 6 * blockIdx.z);   // 0..3455, x fastest
    int w = (flat & 7) * 432 + (flat >> 3);    // per-XCD contiguous slot run
    int n0 = (w % 6) * 128;                    // out-ch block (fastest within XCD)
    int m0 = ((w / 6) % 72) * 128;             // pix block
    int b  = w / 432;                          // == xcd: one batch per XCD
    int tid = threadIdx.x, lane = tid & 63, wave = tid >> 6;
    int ll = lane & 15;
    __shared__ __align__(16) char smem[34816];
    char* As = smem;             // [128 pix][64 ch] bf16, rows 128 B, XOR-swizzled
    char* Bs = smem + 16384;     // [128 ch ][64 k] bf16, linear
    const float* xb = x + (size_t)b * 256 * NPIX;

    f4 acc[4][4] = {};
    int wm = (wave & 1) * 64, wn = (wave >> 1) * 64;

    int pix8  = (tid & 15) * 8;                 // 8 consecutive pix per thread
    int cbase = tid >> 4;                       // ch-pair group 0..15
    unsigned wsw = (unsigned)((tid & 3) << 5);  // ((pix>>3)&3)<<5, lane-constant

    for (int k0 = 0; k0 < 256; k0 += 64) {
        __syncthreads();
        // ---- B staging (global_load_lds, 16B)
        #pragma unroll
        for (int i = 0; i < 4; ++i) {
            int c = wave * 4 + i;   // chunk: 8 rows x 128B = 1 KB
            gload_lds16(Wb + (size_t)(n0 + c * 8 + (lane >> 3)) * 256 + k0 + (lane & 7) * 8,
                        Bs + c * 1024);
        }
        // ---- A staging: x fp32 -> transpose+convert -> As bf16
        #pragma unroll
        for (int cc = 0; cc < 2; ++cc) {
            int c = cbase + cc * 16;            // ch-pair index 0..31
            const float* r0p = xb + (size_t)(k0 + 2 * c) * NPIX + m0 + pix8;
            f4 a0 = *(const f4*)(r0p);
            f4 a1 = *(const f4*)(r0p + 4);
            f4 b0 = *(const f4*)(r0p + NPIX);
            f4 b1 = *(const f4*)(r0p + NPIX + 4);
            int rowb = pix8 * 128 + c * 4;
            #pragma unroll
            for (int j = 0; j < 4; ++j) {
                unsigned w0, w1;
                asm("v_cvt_pk_bf16_f32 %0, %1, %2" : "=v"(w0) : "v"(a0[j]), "v"(b0[j]));
                asm("v_cvt_pk_bf16_f32 %0, %1, %2" : "=v"(w1) : "v"(a1[j]), "v"(b1[j]));
                *(unsigned*)(As + ((rowb + j * 128) ^ wsw))       = w0;
                *(unsigned*)(As + ((rowb + (j + 4) * 128) ^ wsw)) = w1;
            }
        }
        __syncthreads();
        // ---- MFMA over the staged tile
        #pragma unroll
        for (int ks = 0; ks < 2; ++ks) {
            bh8 af[4], bf[4];
            #pragma unroll
            for (int i = 0; i < 4; ++i) {
                int row = wm + i * 16 + ll;
                unsigned rsw = (unsigned)(((row >> 3) & 3) << 5);
                af[i] = *(const bh8*)(As + ((row * 128 + ks * 64 + (lane >> 4) * 16) ^ rsw));
            }
            #pragma unroll
            for (int j = 0; j < 4; ++j)
                bf[j] = *(const bh8*)(Bs + (wn + j * 16 + ll) * 128 + ks * 64 + (lane >> 4) * 16);
            #pragma unroll
            for (int i = 0; i < 4; ++i)
                #pragma unroll
                for (int j = 0; j < 4; ++j)
                    acc[i][j] = __builtin_amdgcn_mfma_f32_16x16x32_bf16(af[i], bf[j], acc[i][j], 0, 0, 0);
        }
    }

    // ---- epilogue: acc -> LDS bf16 tile [128][136] -> coalesced int4 stores
    __syncthreads();
    unsigned short* ts = (unsigned short*)smem;
    bool isQ = (n0 < 256);
    float osc = isQ ? PSL : 1.0f;              // pre-scale Q for log2-domain logits
    int q4 = (lane >> 4) * 4;
    #pragma unroll
    for (int i = 0; i < 4; ++i) {
        #pragma unroll
        for (int j = 0; j < 4; ++j) {
            int ch = wn + j * 16 + ll;
            #pragma unroll
            for (int r = 0; r < 4; ++r)
                ts[(wm + i * 16 + q4 + r) * 136 + ch] = f2bf(acc[i][j][r] * osc);
        }
    }
    __syncthreads();
    #pragma unroll
    for (int it = 0; it < 8; ++it) {
        int e = it * 256 + tid;
        int pixl = e >> 4, ck = (e & 15) * 8;
        int4 v = *(const int4*)&ts[pixl * 136 + ck];
        int pix = m0 + pixl, ch = n0 + ck;
        if (isQ) {
            int head = ch >> 5, d = ch & 31;
            *(int4*)&qb[((size_t)(b * 8 + head) * NPIX + pix) * 32 + d] = v;
        } else {
            int c = ch - 256, head = c >> 6, dv = c & 63;
            *(int4*)&kvb[((size_t)(b * 8 + head) * NPIX + pix) * 64 + dv] = v;
        }
    }
}

// ---------------------------------------------------------------------------
// Kernel 2: halo attention — byte-identical to round-7 (passing, 91.7 us).
// ---------------------------------------------------------------------------
__global__ __launch_bounds__(256, 4) void attn_kernel(const unsigned short* __restrict__ qbuf,
                                                      const unsigned short* __restrict__ kvbuf,
                                                      const unsigned short* __restrict__ relb,
                                                      float* __restrict__ out) {
    int flat = blockIdx.x + 144 * blockIdx.y;       // 0..9215, x fastest
    int w = (flat & 7) * 1152 + (flat >> 3);        // XCD gets 8 full bh planes
    int nbid = w % 144, bh = w / 144;
    int b = bh >> 3, head = bh & 7;
    int hb = nbid / 12, wblk = nbid % 12;
    int r0 = hb * 8, c0 = wblk * 8;
    int tid = threadIdx.x, lane = tid & 63, wave = tid >> 6;
    int ll = lane & 15, lq = lane >> 4;
    int m0 = wave * 16;

    __shared__ __align__(16) char smem[32512];
    unsigned short* Vt = (unsigned short*)smem;                 // [32][224]
    unsigned short* Ks = (unsigned short*)(smem + 14336);       // [224][40]
    char* strip = smem + 14336 + wave * 4352;
    float*          RhTw = (float*)strip;                       // [28][20]
    float*          Rww  = (float*)(strip + 2240);              // [16][23]
    unsigned short* Ps   = (unsigned short*)strip;              // [16][136] overlay
    float*          smR  = (float*)(smem + 32256);

    const unsigned short* qb  = qbuf  + (size_t)bh * NPIX * 32;
    const unsigned short* kvb = kvbuf + (size_t)bh * NPIX * 64;

    // ---- Q fragment straight from global (A-operand layout; pre-scaled PSL)
    int qp0 = m0 + ll;
    int pixq = (r0 + (qp0 >> 3)) * 96 + c0 + (qp0 & 7);
    bh8 aq = *(const bh8*)&qb[(size_t)pixq * 32 + lq * 8];

    // ---- stage K: 224 rows x 64 B, pad/halo-zeroed
    for (int e = tid; e < 896; e += 256) {
        int kp = e >> 2, part = e & 3;
        int a = kp >> 4, b2 = kp & 15;
        int gr = r0 + a - 3, gc = c0 + b2 - 3;
        int4 v = {0, 0, 0, 0};
        if (b2 < 14 && (unsigned)gr < 96u && (unsigned)gc < 96u)
            v = *(const int4*)&kvb[(size_t)(gr * 96 + gc) * 64 + part * 8];
        *(int4*)&Ks[kp * 40 + part * 8] = v;
    }

    // ---- stage V transposed: Vt[d][granule-swizzled kp], pair-packed b32
    #pragma unroll
    for (int it = 0; it < 2; ++it) {
        int e = it * 256 + tid;
        int part = e >> 7, kp2 = e & 127;
        if (kp2 < 112) {
            int a = kp2 >> 3, b2 = (kp2 & 7) * 2;
            int gr = r0 + a - 3, gc = c0 + b2 - 3;
            int4 lo = {0, 0, 0, 0}, hi = {0, 0, 0, 0};
            bool rok = ((kp2 & 7) < 7) && ((unsigned)gr < 96u);
            if (rok && (unsigned)gc < 96u)
                lo = *(const int4*)&kvb[(size_t)(gr * 96 + gc) * 64 + 32 + part * 8];
            if (rok && (unsigned)(gc + 1) < 96u)
                hi = *(const int4*)&kvb[(size_t)(gr * 96 + gc + 1) * 64 + 32 + part * 8];
            int g = kp2 >> 2, kb = b2 & 7;
            const unsigned* lw = (const unsigned*)&lo;
            const unsigned* hw = (const unsigned*)&hi;
            #pragma unroll
            for (int jw = 0; jw < 4; ++jw) {
                unsigned l2 = lw[jw], h2 = hw[jw];
                unsigned v0 = (l2 & 0xffffu) | (h2 << 16);
                unsigned v1 = (l2 >> 16) | (h2 & 0xffff0000u);
                int d0 = part * 8 + jw * 2;
                int s0 = (((jw * 2) & 3) + part) & 3;
                int s1 = (((jw * 2 + 1) & 3) + part) & 3;
                *(unsigned*)&Vt[d0 * 224 + ((g ^ s0) * 8) + kb] = v0;
                *(unsigned*)&Vt[(d0 + 1) * 224 + ((g ^ s1) * 8) + kb] = v1;
            }
        }
    }

    __syncthreads();                               // S1: Ks/Vt staging visible

    // ---- S = Q K^T (14 MFMAs from staged Ks)
    f4 zero4 = {0.f, 0.f, 0.f, 0.f};
    f4 S[14];
    #pragma unroll
    for (int t = 0; t < 14; ++t) {
        bh8 bk = *(const bh8*)&Ks[(t * 16 + ll) * 40 + lq * 8];
        S[t] = __builtin_amdgcn_mfma_f32_16x16x32_bf16(aq, bk, zero4, 0, 0, 0);
    }

    __syncthreads();                               // S1b: all waves done with Ks

    // ---- rel dot-products via MFMA -> wave-private strips (overlay Ks)
    #pragma unroll
    for (int t = 0; t < 2; ++t) {
        int r = t * 16 + ll;
        bh8 hbv = *(const bh8*)&relb[(size_t)r * 32 + lq * 8];
        bh8 wbv = *(const bh8*)&relb[1024 + (size_t)r * 32 + lq * 8];
        f4 ch = __builtin_amdgcn_mfma_f32_16x16x32_bf16(aq, hbv, zero4, 0, 0, 0);
        f4 cw = __builtin_amdgcn_mfma_f32_16x16x32_bf16(aq, wbv, zero4, 0, 0, 0);
        if (r < 28) *(f4*)&RhTw[r * 20 + lq * 4] = ch;
        if (r >= 6 && r < 27) {
            #pragma unroll
            for (int rr = 0; rr < 4; ++rr)
                Rww[(lq * 4 + rr) * 23 + (r - 6)] = cw[rr];
        }
    }

    // ---- logits (log2 domain; Q pre-scaled so lg = S + rh + rw), row sums
    int row0 = m0 + lq * 4;
    int h = row0 >> 3;                             // quad-uniform
    bool valid = (ll < 14);
    float rw4[4];
    #pragma unroll
    for (int rr = 0; rr < 4; ++rr) {
        int row = row0 + rr;
        rw4[rr] = valid ? Rww[(lq * 4 + rr) * 23 + 7 + ll - (row & 7)] : -INFINITY;
    }
    float sm4[4] = {0.f, 0.f, 0.f, 0.f};
    #pragma unroll
    for (int t = 0; t < 14; ++t) {
        f4 rh = *(const f4*)&RhTw[(13 + t - h) * 20 + lq * 4];
        #pragma unroll
        for (int rr = 0; rr < 4; ++rr) {
            float lg = (S[t][rr] + rh[rr]) + rw4[rr];
            float p = __builtin_amdgcn_exp2f(lg);
            S[t][rr] = p;
            sm4[rr] += p;
        }
    }
    #pragma unroll
    for (int rr = 0; rr < 4; ++rr) {
        sm4[rr] += __shfl_xor(sm4[rr], 1);
        sm4[rr] += __shfl_xor(sm4[rr], 2);
        sm4[rr] += __shfl_xor(sm4[rr], 4);
        sm4[rr] += __shfl_xor(sm4[rr], 8);
    }
    if (ll == 0) {
        #pragma unroll
        for (int rr = 0; rr < 4; ++rr) smR[row0 + rr] = sm4[rr];
    }
    // no barrier: strip + smR rows are wave-private; same-wave DS ops in-order.

    // ---- 2-chunk P->LDS (cvt_pk pairs, b32 writes) + PV
    int sel = ll & 1;
    int rowA = lq * 4 + sel * 2;                   // this lane writes rows rowA, rowA+1
    f4 O[2] = {zero4, zero4};
    #pragma unroll
    for (int c = 0; c < 2; ++c) {
        const int nt = c ? 6 : 8;
        #pragma unroll
        for (int tl = 0; tl < 8; ++tl) {
            if (tl < nt) {
                int t = c * 8 + tl;
                float o0 = S[t][0], o1 = S[t][1], o2 = S[t][2], o3 = S[t][3];
                float q0 = __shfl_xor(o0, 1), q1 = __shfl_xor(o1, 1);
                float q2 = __shfl_xor(o2, 1), q3 = __shfl_xor(o3, 1);
                float lo0 = sel ? q2 : o0, hi0 = sel ? o2 : q0;
                float lo1 = sel ? q3 : o1, hi1 = sel ? o3 : q1;
                unsigned w0, w1;
                asm("v_cvt_pk_bf16_f32 %0, %1, %2" : "=v"(w0) : "v"(lo0), "v"(hi0));
                asm("v_cvt_pk_bf16_f32 %0, %1, %2" : "=v"(w1) : "v"(lo1), "v"(hi1));
                int colp = tl * 16 + (ll & ~1);
                *(unsigned*)&Ps[rowA * 136 + colp]       = w0;
                *(unsigned*)&Ps[(rowA + 1) * 136 + colp] = w1;
            }
        }
        const int nkt = c ? 3 : 4;
        #pragma unroll
        for (int ktl = 0; ktl < 4; ++ktl) {
            if (ktl < nkt) {
                int kt = c * 4 + ktl;
                bh8 bp = *(const bh8*)&Ps[ll * 136 + ktl * 32 + lq * 8];
                #pragma unroll
                for (int mt = 0; mt < 2; ++mt) {
                    int d = mt * 16 + ll;
                    int s = ((d & 3) + ((d >> 3) & 3)) & 3;
                    bh8 av = *(const bh8*)&Vt[d * 224 + (((kt * 4 + lq) ^ s) * 8)];
                    O[mt] = __builtin_amdgcn_mfma_f32_16x16x32_bf16(av, bp, O[mt], 0, 0, 0);
                }
            }
        }
    }

    // ---- epilogue: O^T lanes are pixel-consecutive -> coalesced-8 stores
    int qp = m0 + ll;
    float rs = 1.0f / smR[qp];
    int pix = (r0 + (qp >> 3)) * 96 + c0 + (qp & 7);
    float* ob = out + (size_t)(b * 256 + head * 32) * NPIX;
    #pragma unroll
    for (int mt = 0; mt < 2; ++mt) {
        #pragma unroll
        for (int rr = 0; rr < 4; ++rr) {
            int d = mt * 16 + lq * 4 + rr;
            ob[(size_t)d * NPIX + pix] = O[mt][rr] * rs;
        }
    }
}

extern "C" void kernel_launch(void* const* d_in, const int* in_sizes, int n_in,
                              void* d_out, int out_size, void* d_ws, size_t ws_size,
                              hipStream_t stream) {
    const float* x    = (const float*)d_in[0];
    const float* qw   = (const float*)d_in[1];
    const float* kvw  = (const float*)d_in[2];
    const float* hrel = (const float*)d_in[3];
    const float* wrel = (const float*)d_in[4];
    float* out = (float*)d_out;

    char* ws = (char*)d_ws;
    unsigned short* Wb    = (unsigned short*)ws;                 //    393,216 B
    unsigned short* relb  = (unsigned short*)(ws + 393216);      //      4,096 B
    unsigned short* qbuf  = (unsigned short*)(ws + 397312);      // 37,748,736 B
    unsigned short* kvbuf = (unsigned short*)(ws + 38146048);    // 75,497,472 B

    wconv_kernel<<<dim3(776), 256, 0, stream>>>(qw, kvw, hrel, wrel, Wb, relb);
    proj_kernel<<<dim3(72, 6, 8), 256, 0, stream>>>(x, Wb, qbuf, kvbuf);
    attn_kernel<<<dim3(144, 64), 256, 0, stream>>>(qbuf, kvbuf, relb, out);
}

// Round 9
// 264.180 us; speedup vs baseline: 1.0576x; 1.0576x over previous
//
#include <hip/hip_runtime.h>
#include <math.h>

#define NPIX 9216        // 96*96
#define SCALE 0.17677669529663687f
#define LOG2E 1.4426950408889634f
#define PSL   (SCALE * LOG2E)            // baked into Q at proj epilogue
#define RINV  5.656854249492381f         // 1/SCALE, baked into relb

typedef __attribute__((ext_vector_type(8))) short bh8;   // 8 x bf16 (4 VGPRs)
typedef __attribute__((ext_vector_type(4))) float f4;    // MFMA C/D

__device__ __forceinline__ unsigned short f2bf(float f) {
    unsigned u = __float_as_uint(f);
    u += 0x7fff + ((u >> 16) & 1);          // RNE
    return (unsigned short)(u >> 16);
}
__device__ __forceinline__ void gload_lds16(const void* g, void* l) {
    __builtin_amdgcn_global_load_lds(
        (const __attribute__((address_space(1))) unsigned int*)g,
        (__attribute__((address_space(3))) unsigned int*)l, 16, 0, 0);
}

// ---------------------------------------------------------------------------
// Kernel 0: W (q;kv) fp32 -> bf16 [768][256]; blocks 768+: hrel/wrel fp32 ->
// bf16 relb[2][32][32], pre-scaled by 1/SCALE (Q carries SCALE*LOG2E),
// rows >=27 zeroed.
// ---------------------------------------------------------------------------
__global__ void wconv_kernel(const float* __restrict__ qw, const float* __restrict__ kvw,
                             const float* __restrict__ hrel, const float* __restrict__ wrel,
                             unsigned short* __restrict__ Wb,
                             unsigned short* __restrict__ relb) {
    int bid = blockIdx.x, tid = threadIdx.x;
    if (bid < 768) {
        float v = (bid < 256) ? qw[bid * 256 + tid] : kvw[(bid - 256) * 256 + tid];
        Wb[bid * 256 + tid] = f2bf(v);
    } else {
        int e = (bid - 768) * 256 + tid;      // [0, 2048)
        int half = e >> 10, r = (e >> 5) & 31, d = e & 31;
        float v = 0.0f;
        if (r < 27) v = (half ? wrel : hrel)[r * 32 + d] * RINV;
        relb[half * 1024 + r * 32 + d] = f2bf(v);
    }
}

// ---------------------------------------------------------------------------
// Kernel 1: x[b][256][9216] fp32 -> xt[b][9216][256] bf16 (transpose+convert).
// LDS tile [128 pix][128 ch], XOR-swizzled byte ^= ((row>>3)&7)<<4.
// (round-7 version, measured as part of a passing 265.9 us run)
// ---------------------------------------------------------------------------
__global__ __launch_bounds__(256) void xtrans_kernel(const float* __restrict__ x,
                                                     unsigned short* __restrict__ xt) {
    int b = blockIdx.z;
    int p0 = blockIdx.x * 128, c0 = blockIdx.y * 128;
    int tid = threadIdx.x;
    __shared__ __align__(16) unsigned short ts[128 * 128];
    const float* xb = x + (size_t)b * 256 * NPIX;
    #pragma unroll
    for (int it = 0; it < 16; ++it) {
        int e = it * 256 + tid;
        int ch = e >> 5, p4 = (e & 31) * 4;
        float4 v = *(const float4*)(xb + (size_t)(c0 + ch) * NPIX + p0 + p4);
        int sw = ((p4 >> 3) & 7) << 4;               // row>>3 constant over j=0..3
        char* tb = (char*)ts;
        *(unsigned short*)(tb + (((p4 + 0) * 256 + ch * 2) ^ sw)) = f2bf(v.x);
        *(unsigned short*)(tb + (((p4 + 1) * 256 + ch * 2) ^ sw)) = f2bf(v.y);
        *(unsigned short*)(tb + (((p4 + 2) * 256 + ch * 2) ^ sw)) = f2bf(v.z);
        *(unsigned short*)(tb + (((p4 + 3) * 256 + ch * 2) ^ sw)) = f2bf(v.w);
    }
    __syncthreads();
    unsigned short* xtb = xt + (size_t)b * NPIX * 256;
    #pragma unroll
    for (int it = 0; it < 8; ++it) {
        int e = it * 256 + tid;
        int p = e >> 4, ck = (e & 15) * 8;
        int bo = (p * 256 + ck * 2) ^ (((p >> 3) & 7) << 4);
        *(int4*)(xtb + (size_t)(p0 + p) * 256 + c0 + ck) = *(const int4*)((char*)ts + bo);
    }
}

// ---------------------------------------------------------------------------
// Kernel 2: projection GEMM, round-7 staged structure + NEW: conflict-free
// LDS fragment reads via source-pre-swizzle (guide rule 21 / T2):
//   - gload_lds16 dest stays linear (lane x 16B); the GLOBAL source column
//     is permuted: col8 = (lane&7) ^ (lane>>3)  (same 128B segment, so
//     coalescing is unchanged). LDS then holds content[row][col ^ (row&7)].
//   - af/bf b128 reads XOR byte addr with ((row&7)<<4): the 16 lanes that
//     previously all hit banks 0-3 (16-way, §6 G4) now spread across 8
//     16B slots -> 2-way (free).
// Epilogue unchanged; Q pre-scaled by PSL.
// ---------------------------------------------------------------------------
__global__ __launch_bounds__(256) void proj_kernel(const unsigned short* __restrict__ xt,
                                                   const unsigned short* __restrict__ Wb,
                                                   unsigned short* __restrict__ qb,
                                                   unsigned short* __restrict__ kvb) {
    int flat = blockIdx.x + 72 * (blockIdx.y + 6 * blockIdx.z);   // 0..3455, x fastest
    int w = (flat & 7) * 432 + (flat >> 3);    // per-XCD contiguous slot run
    int n0 = (w % 6) * 128;                    // out-ch block (fastest within XCD)
    int m0 = ((w / 6) % 72) * 128;             // pix block
    int b  = w / 432;                          // == xcd: one batch per XCD
    int tid = threadIdx.x, lane = tid & 63, wave = tid >> 6;
    int ll = lane & 15;
    __shared__ __align__(16) char smem[34816];
    char* As = smem;             // [128 pix][64 k] bf16, rows 128 B, col^(row&7)
    char* Bs = smem + 16384;     // [128 ch ][64 k] bf16, col^(row&7)
    const unsigned short* xtb = xt + (size_t)b * NPIX * 256;

    f4 acc[4][4] = {};
    int wm = (wave & 1) * 64, wn = (wave >> 1) * 64;
    int scol = ((lane & 7) ^ (lane >> 3)) * 8;   // pre-swizzled source column

    for (int k0 = 0; k0 < 256; k0 += 64) {
        __syncthreads();
        #pragma unroll
        for (int i = 0; i < 4; ++i) {
            int c = wave * 4 + i;   // chunk: 8 rows x 128B = 1 KB
            gload_lds16(xtb + (size_t)(m0 + c * 8 + (lane >> 3)) * 256 + k0 + scol,
                        As + c * 1024);
            gload_lds16(Wb + (size_t)(n0 + c * 8 + (lane >> 3)) * 256 + k0 + scol,
                        Bs + c * 1024);
        }
        __syncthreads();
        #pragma unroll
        for (int ks = 0; ks < 2; ++ks) {
            bh8 af[4], bf[4];
            #pragma unroll
            for (int i = 0; i < 4; ++i) {
                int ra = wm + i * 16 + ll;
                af[i] = *(const bh8*)(As + ((ra * 128 + ks * 64 + (lane >> 4) * 16)
                                            ^ ((ra & 7) << 4)));
            }
            #pragma unroll
            for (int j = 0; j < 4; ++j) {
                int rb = wn + j * 16 + ll;
                bf[j] = *(const bh8*)(Bs + ((rb * 128 + ks * 64 + (lane >> 4) * 16)
                                            ^ ((rb & 7) << 4)));
            }
            #pragma unroll
            for (int i = 0; i < 4; ++i)
                #pragma unroll
                for (int j = 0; j < 4; ++j)
                    acc[i][j] = __builtin_amdgcn_mfma_f32_16x16x32_bf16(af[i], bf[j], acc[i][j], 0, 0, 0);
        }
    }

    // ---- epilogue: acc -> LDS bf16 tile [128][136] -> coalesced int4 stores
    __syncthreads();
    unsigned short* ts = (unsigned short*)smem;
    bool isQ = (n0 < 256);
    float osc = isQ ? PSL : 1.0f;              // pre-scale Q for log2-domain logits
    int q4 = (lane >> 4) * 4;
    #pragma unroll
    for (int i = 0; i < 4; ++i) {
        #pragma unroll
        for (int j = 0; j < 4; ++j) {
            int ch = wn + j * 16 + ll;
            #pragma unroll
            for (int r = 0; r < 4; ++r)
                ts[(wm + i * 16 + q4 + r) * 136 + ch] = f2bf(acc[i][j][r] * osc);
        }
    }
    __syncthreads();
    #pragma unroll
    for (int it = 0; it < 8; ++it) {
        int e = it * 256 + tid;
        int pixl = e >> 4, ck = (e & 15) * 8;
        int4 v = *(const int4*)&ts[pixl * 136 + ck];
        int pix = m0 + pixl, ch = n0 + ck;
        if (isQ) {
            int head = ch >> 5, d = ch & 31;
            *(int4*)&qb[((size_t)(b * 8 + head) * NPIX + pix) * 32 + d] = v;
        } else {
            int c = ch - 256, head = c >> 6, dv = c & 63;
            *(int4*)&kvb[((size_t)(b * 8 + head) * NPIX + pix) * 64 + dv] = v;
        }
    }
}

// ---------------------------------------------------------------------------
// Kernel 3: halo attention — byte-identical to round-8 (passing, 91.7 us).
// ---------------------------------------------------------------------------
__global__ __launch_bounds__(256, 4) void attn_kernel(const unsigned short* __restrict__ qbuf,
                                                      const unsigned short* __restrict__ kvbuf,
                                                      const unsigned short* __restrict__ relb,
                                                      float* __restrict__ out) {
    int flat = blockIdx.x + 144 * blockIdx.y;       // 0..9215, x fastest
    int w = (flat & 7) * 1152 + (flat >> 3);        // XCD gets 8 full bh planes
    int nbid = w % 144, bh = w / 144;
    int b = bh >> 3, head = bh & 7;
    int hb = nbid / 12, wblk = nbid % 12;
    int r0 = hb * 8, c0 = wblk * 8;
    int tid = threadIdx.x, lane = tid & 63, wave = tid >> 6;
    int ll = lane & 15, lq = lane >> 4;
    int m0 = wave * 16;

    __shared__ __align__(16) char smem[32512];
    unsigned short* Vt = (unsigned short*)smem;                 // [32][224]
    unsigned short* Ks = (unsigned short*)(smem + 14336);       // [224][40]
    char* strip = smem + 14336 + wave * 4352;
    float*          RhTw = (float*)strip;                       // [28][20]
    float*          Rww  = (float*)(strip + 2240);              // [16][23]
    unsigned short* Ps   = (unsigned short*)strip;              // [16][136] overlay
    float*          smR  = (float*)(smem + 32256);

    const unsigned short* qb  = qbuf  + (size_t)bh * NPIX * 32;
    const unsigned short* kvb = kvbuf + (size_t)bh * NPIX * 64;

    // ---- Q fragment straight from global (A-operand layout; pre-scaled PSL)
    int qp0 = m0 + ll;
    int pixq = (r0 + (qp0 >> 3)) * 96 + c0 + (qp0 & 7);
    bh8 aq = *(const bh8*)&qb[(size_t)pixq * 32 + lq * 8];

    // ---- stage K: 224 rows x 64 B, pad/halo-zeroed
    for (int e = tid; e < 896; e += 256) {
        int kp = e >> 2, part = e & 3;
        int a = kp >> 4, b2 = kp & 15;
        int gr = r0 + a - 3, gc = c0 + b2 - 3;
        int4 v = {0, 0, 0, 0};
        if (b2 < 14 && (unsigned)gr < 96u && (unsigned)gc < 96u)
            v = *(const int4*)&kvb[(size_t)(gr * 96 + gc) * 64 + part * 8];
        *(int4*)&Ks[kp * 40 + part * 8] = v;
    }

    // ---- stage V transposed: Vt[d][granule-swizzled kp], pair-packed b32
    #pragma unroll
    for (int it = 0; it < 2; ++it) {
        int e = it * 256 + tid;
        int part = e >> 7, kp2 = e & 127;
        if (kp2 < 112) {
            int a = kp2 >> 3, b2 = (kp2 & 7) * 2;
            int gr = r0 + a - 3, gc = c0 + b2 - 3;
            int4 lo = {0, 0, 0, 0}, hi = {0, 0, 0, 0};
            bool rok = ((kp2 & 7) < 7) && ((unsigned)gr < 96u);
            if (rok && (unsigned)gc < 96u)
                lo = *(const int4*)&kvb[(size_t)(gr * 96 + gc) * 64 + 32 + part * 8];
            if (rok && (unsigned)(gc + 1) < 96u)
                hi = *(const int4*)&kvb[(size_t)(gr * 96 + gc + 1) * 64 + 32 + part * 8];
            int g = kp2 >> 2, kb = b2 & 7;
            const unsigned* lw = (const unsigned*)&lo;
            const unsigned* hw = (const unsigned*)&hi;
            #pragma unroll
            for (int jw = 0; jw < 4; ++jw) {
                unsigned l2 = lw[jw], h2 = hw[jw];
                unsigned v0 = (l2 & 0xffffu) | (h2 << 16);
                unsigned v1 = (l2 >> 16) | (h2 & 0xffff0000u);
                int d0 = part * 8 + jw * 2;
                int s0 = (((jw * 2) & 3) + part) & 3;
                int s1 = (((jw * 2 + 1) & 3) + part) & 3;
                *(unsigned*)&Vt[d0 * 224 + ((g ^ s0) * 8) + kb] = v0;
                *(unsigned*)&Vt[(d0 + 1) * 224 + ((g ^ s1) * 8) + kb] = v1;
            }
        }
    }

    __syncthreads();                               // S1: Ks/Vt staging visible

    // ---- S = Q K^T (14 MFMAs from staged Ks)
    f4 zero4 = {0.f, 0.f, 0.f, 0.f};
    f4 S[14];
    #pragma unroll
    for (int t = 0; t < 14; ++t) {
        bh8 bk = *(const bh8*)&Ks[(t * 16 + ll) * 40 + lq * 8];
        S[t] = __builtin_amdgcn_mfma_f32_16x16x32_bf16(aq, bk, zero4, 0, 0, 0);
    }

    __syncthreads();                               // S1b: all waves done with Ks

    // ---- rel dot-products via MFMA -> wave-private strips (overlay Ks)
    #pragma unroll
    for (int t = 0; t < 2; ++t) {
        int r = t * 16 + ll;
        bh8 hbv = *(const bh8*)&relb[(size_t)r * 32 + lq * 8];
        bh8 wbv = *(const bh8*)&relb[1024 + (size_t)r * 32 + lq * 8];
        f4 ch = __builtin_amdgcn_mfma_f32_16x16x32_bf16(aq, hbv, zero4, 0, 0, 0);
        f4 cw = __builtin_amdgcn_mfma_f32_16x16x32_bf16(aq, wbv, zero4, 0, 0, 0);
        if (r < 28) *(f4*)&RhTw[r * 20 + lq * 4] = ch;
        if (r >= 6 && r < 27) {
            #pragma unroll
            for (int rr = 0; rr < 4; ++rr)
                Rww[(lq * 4 + rr) * 23 + (r - 6)] = cw[rr];
        }
    }

    // ---- logits (log2 domain; Q pre-scaled so lg = S + rh + rw), row sums
    int row0 = m0 + lq * 4;
    int h = row0 >> 3;                             // quad-uniform
    bool valid = (ll < 14);
    float rw4[4];
    #pragma unroll
    for (int rr = 0; rr < 4; ++rr) {
        int row = row0 + rr;
        rw4[rr] = valid ? Rww[(lq * 4 + rr) * 23 + 7 + ll - (row & 7)] : -INFINITY;
    }
    float sm4[4] = {0.f, 0.f, 0.f, 0.f};
    #pragma unroll
    for (int t = 0; t < 14; ++t) {
        f4 rh = *(const f4*)&RhTw[(13 + t - h) * 20 + lq * 4];
        #pragma unroll
        for (int rr = 0; rr < 4; ++rr) {
            float lg = (S[t][rr] + rh[rr]) + rw4[rr];
            float p = __builtin_amdgcn_exp2f(lg);
            S[t][rr] = p;
            sm4[rr] += p;
        }
    }
    #pragma unroll
    for (int rr = 0; rr < 4; ++rr) {
        sm4[rr] += __shfl_xor(sm4[rr], 1);
        sm4[rr] += __shfl_xor(sm4[rr], 2);
        sm4[rr] += __shfl_xor(sm4[rr], 4);
        sm4[rr] += __shfl_xor(sm4[rr], 8);
    }
    if (ll == 0) {
        #pragma unroll
        for (int rr = 0; rr < 4; ++rr) smR[row0 + rr] = sm4[rr];
    }
    // no barrier: strip + smR rows are wave-private; same-wave DS ops in-order.

    // ---- 2-chunk P->LDS (cvt_pk pairs, b32 writes) + PV
    int sel = ll & 1;
    int rowA = lq * 4 + sel * 2;                   // this lane writes rows rowA, rowA+1
    f4 O[2] = {zero4, zero4};
    #pragma unroll
    for (int c = 0; c < 2; ++c) {
        const int nt = c ? 6 : 8;
        #pragma unroll
        for (int tl = 0; tl < 8; ++tl) {
            if (tl < nt) {
                int t = c * 8 + tl;
                float o0 = S[t][0], o1 = S[t][1], o2 = S[t][2], o3 = S[t][3];
                float q0 = __shfl_xor(o0, 1), q1 = __shfl_xor(o1, 1);
                float q2 = __shfl_xor(o2, 1), q3 = __shfl_xor(o3, 1);
                float lo0 = sel ? q2 : o0, hi0 = sel ? o2 : q0;
                float lo1 = sel ? q3 : o1, hi1 = sel ? o3 : q1;
                unsigned w0, w1;
                asm("v_cvt_pk_bf16_f32 %0, %1, %2" : "=v"(w0) : "v"(lo0), "v"(hi0));
                asm("v_cvt_pk_bf16_f32 %0, %1, %2" : "=v"(w1) : "v"(lo1), "v"(hi1));
                int colp = tl * 16 + (ll & ~1);
                *(unsigned*)&Ps[rowA * 136 + colp]       = w0;
                *(unsigned*)&Ps[(rowA + 1) * 136 + colp] = w1;
            }
        }
        const int nkt = c ? 3 : 4;
        #pragma unroll
        for (int ktl = 0; ktl < 4; ++ktl) {
            if (ktl < nkt) {
                int kt = c * 4 + ktl;
                bh8 bp = *(const bh8*)&Ps[ll * 136 + ktl * 32 + lq * 8];
                #pragma unroll
                for (int mt = 0; mt < 2; ++mt) {
                    int d = mt * 16 + ll;
                    int s = ((d & 3) + ((d >> 3) & 3)) & 3;
                    bh8 av = *(const bh8*)&Vt[d * 224 + (((kt * 4 + lq) ^ s) * 8)];
                    O[mt] = __builtin_amdgcn_mfma_f32_16x16x32_bf16(av, bp, O[mt], 0, 0, 0);
                }
            }
        }
    }

    // ---- epilogue: O^T lanes are pixel-consecutive -> coalesced-8 stores
    int qp = m0 + ll;
    float rs = 1.0f / smR[qp];
    int pix = (r0 + (qp >> 3)) * 96 + c0 + (qp & 7);
    float* ob = out + (size_t)(b * 256 + head * 32) * NPIX;
    #pragma unroll
    for (int mt = 0; mt < 2; ++mt) {
        #pragma unroll
        for (int rr = 0; rr < 4; ++rr) {
            int d = mt * 16 + lq * 4 + rr;
            ob[(size_t)d * NPIX + pix] = O[mt][rr] * rs;
        }
    }
}

extern "C" void kernel_launch(void* const* d_in, const int* in_sizes, int n_in,
                              void* d_out, int out_size, void* d_ws, size_t ws_size,
                              hipStream_t stream) {
    const float* x    = (const float*)d_in[0];
    const float* qw   = (const float*)d_in[1];
    const float* kvw  = (const float*)d_in[2];
    const float* hrel = (const float*)d_in[3];
    const float* wrel = (const float*)d_in[4];
    float* out = (float*)d_out;

    char* ws = (char*)d_ws;
    unsigned short* xt    = (unsigned short*)ws;                 // 37,748,736 B
    unsigned short* Wb    = (unsigned short*)(ws + 37748736);    //    393,216 B
    unsigned short* relb  = (unsigned short*)(ws + 38141952);    //      4,096 B
    unsigned short* qbuf  = (unsigned short*)(ws + 38146048);    // 37,748,736 B
    unsigned short* kvbuf = (unsigned short*)(ws + 75894784);    // 75,497,472 B

    wconv_kernel<<<dim3(776), 256, 0, stream>>>(qw, kvw, hrel, wrel, Wb, relb);
    xtrans_kernel<<<dim3(72, 2, 8), 256, 0, stream>>>(x, xt);
    proj_kernel<<<dim3(72, 6, 8), 256, 0, stream>>>(xt, Wb, qbuf, kvbuf);
    attn_kernel<<<dim3(144, 64), 256, 0, stream>>>(qbuf, kvbuf, relb, out);
}